// Round 2
// baseline (263.964 us; speedup 1.0000x reference)
//
#include <hip/hip_runtime.h>

// ---------------------------------------------------------------------------
// InterpNetwork: G=2 graphs, T=33 steps, D=96 nodes/graph, H=128, PROJ=128.
// Decomposition: feat@ud_W1 = P[t+1,i] + Q[t,j] + C[i,j]  (concat split),
// so per-edge work is only layer2 (128->64) + layer3 (64->1) via MFMA.
// ---------------------------------------------------------------------------

typedef __bf16 bf16_t;
typedef bf16_t bf16x8 __attribute__((ext_vector_type(8)));
typedef bf16_t bf16x2 __attribute__((ext_vector_type(2)));
typedef float  f32x4  __attribute__((ext_vector_type(4)));
typedef float  f32x2  __attribute__((ext_vector_type(2)));

#define XS_LD 136           // padded LDS leading dim (bf16 elems): 272B rows, 16B aligned
#define NEGV  -1000000000.0f

// ---------------------------------------------------------------------------
// K0: transpose weights to [N][K] row-major bf16 so B-fragments are
// 8-contiguous-K bf16x8 loads.
// ---------------------------------------------------------------------------
__global__ __launch_bounds__(256) void k0_prep(
    const float* __restrict__ neW1, const float* __restrict__ neW2,
    const float* __restrict__ udW1, const float* __restrict__ udW2,
    const float* __restrict__ dpW1, const float* __restrict__ dpW2,
    bf16_t* __restrict__ neW1T, bf16_t* __restrict__ neW2T,
    bf16_t* __restrict__ udW1aT, bf16_t* __restrict__ udW1bT,
    bf16_t* __restrict__ udW2T, bf16_t* __restrict__ dpW1T,
    bf16_t* __restrict__ dpW2T, bf16_t* __restrict__ W1cT) {
  int idx = blockIdx.x * 256 + threadIdx.x;
  if (idx < 16384) { int n = idx >> 7, k = idx & 127; neW1T[idx]  = (bf16_t)neW1[k*128+n]; return; }
  idx -= 16384;
  if (idx < 16384) { int n = idx >> 7, k = idx & 127; neW2T[idx]  = (bf16_t)neW2[k*128+n]; return; }
  idx -= 16384;
  if (idx < 16384) { int n = idx >> 7, k = idx & 127; udW1aT[idx] = (bf16_t)udW1[k*128+n]; return; }
  idx -= 16384;
  if (idx < 16384) { int n = idx >> 7, k = idx & 127; udW1bT[idx] = (bf16_t)udW1[(128+k)*128+n]; return; }
  idx -= 16384;
  if (idx < 8192)  { int n = idx >> 7, k = idx & 127; udW2T[idx]  = (bf16_t)udW2[k*64+n]; return; }
  idx -= 8192;
  if (idx < 32768) { int n = idx >> 8, k = idx & 255; dpW1T[idx]  = (bf16_t)dpW1[k*128+n]; return; }
  idx -= 32768;
  if (idx < 8192)  { int n = idx >> 7, k = idx & 127; dpW2T[idx]  = (bf16_t)dpW2[k*64+n]; return; }
  idx -= 8192;
  if (idx < 4096)  { int n = idx >> 5, m = idx & 31;  W1cT[idx]   = (bf16_t)udW1[(256+m)*128+n]; return; }
}

// ---------------------------------------------------------------------------
// K1: node encoder. One block per (g,s), 6 waves, M=96 rows.
//   enc = relu(relu(xT@W1+b1)@W2+b2)  (bf16 out)
//   P   = enc @ ud_W1[0:128]    (fp32 out, used at t+1 on the i side / xne)
//   Q   = enc @ ud_W1[128:256]  (fp32 out, used at t   on the j side / xce)
// ---------------------------------------------------------------------------
__global__ __launch_bounds__(384) void k1_node(
    const float* __restrict__ x,
    const bf16_t* __restrict__ neW1T, const float* __restrict__ neb1,
    const bf16_t* __restrict__ neW2T, const float* __restrict__ neb2,
    const bf16_t* __restrict__ udW1aT, const bf16_t* __restrict__ udW1bT,
    bf16_t* __restrict__ encB, float* __restrict__ P, float* __restrict__ Q) {
  __shared__ bf16_t bufA[96 * XS_LD];
  __shared__ bf16_t bufB[96 * XS_LD];
  int b = blockIdx.x; int g = b / 33, s = b % 33;
  const float* xsrc = x + (size_t)(g*33 + s) * 128 * 192 + g*96;  // [h*192 + d]
  for (int f = threadIdx.x; f < 96*128; f += 384) {
    int d = f % 96, h = f / 96;
    bufA[d * XS_LD + h] = (bf16_t)xsrc[h*192 + d];
  }
  __syncthreads();
  int l = threadIdx.x & 63, w = threadIdx.x >> 6;
  int lr = l & 15, lg = l >> 4;

  // layer1: bufA -> bufB
  {
    bf16x8 a[4];
    #pragma unroll
    for (int ks = 0; ks < 4; ++ks)
      a[ks] = *(const bf16x8*)(bufA + (w*16 + lr)*XS_LD + ks*32 + lg*8);
    #pragma unroll
    for (int nb = 0; nb < 8; ++nb) {
      f32x4 acc = {0.f,0.f,0.f,0.f};
      #pragma unroll
      for (int ks = 0; ks < 4; ++ks) {
        bf16x8 bfr = *(const bf16x8*)(neW1T + (nb*16 + lr)*128 + ks*32 + lg*8);
        acc = __builtin_amdgcn_mfma_f32_16x16x32_bf16(a[ks], bfr, acc, 0, 0, 0);
      }
      int n = nb*16 + lr; float bv = neb1[n];
      #pragma unroll
      for (int r = 0; r < 4; ++r)
        bufB[(w*16 + lg*4 + r)*XS_LD + n] = (bf16_t)fmaxf(acc[r] + bv, 0.f);
    }
  }
  __syncthreads();

  // layer2: bufB -> bufA + encB(global)
  bf16_t* encOut = encB + (size_t)((g*33 + s) * 96) * 128;
  {
    bf16x8 a[4];
    #pragma unroll
    for (int ks = 0; ks < 4; ++ks)
      a[ks] = *(const bf16x8*)(bufB + (w*16 + lr)*XS_LD + ks*32 + lg*8);
    #pragma unroll
    for (int nb = 0; nb < 8; ++nb) {
      f32x4 acc = {0.f,0.f,0.f,0.f};
      #pragma unroll
      for (int ks = 0; ks < 4; ++ks) {
        bf16x8 bfr = *(const bf16x8*)(neW2T + (nb*16 + lr)*128 + ks*32 + lg*8);
        acc = __builtin_amdgcn_mfma_f32_16x16x32_bf16(a[ks], bfr, acc, 0, 0, 0);
      }
      int n = nb*16 + lr; float bv = neb2[n];
      #pragma unroll
      for (int r = 0; r < 4; ++r) {
        bf16_t v = (bf16_t)fmaxf(acc[r] + bv, 0.f);
        int row = w*16 + lg*4 + r;
        bufA[row*XS_LD + n] = v;
        encOut[row*128 + n] = v;
      }
    }
  }
  __syncthreads();

  // P,Q layers from bufA(enc), no bias/relu, fp32 out
  float* Pout = P + (size_t)((g*33 + s) * 96) * 128;
  float* Qout = Q + (size_t)((g*33 + s) * 96) * 128;
  {
    bf16x8 a[4];
    #pragma unroll
    for (int ks = 0; ks < 4; ++ks)
      a[ks] = *(const bf16x8*)(bufA + (w*16 + lr)*XS_LD + ks*32 + lg*8);
    #pragma unroll
    for (int nb = 0; nb < 8; ++nb) {
      f32x4 accP = {0.f,0.f,0.f,0.f};
      f32x4 accQ = {0.f,0.f,0.f,0.f};
      #pragma unroll
      for (int ks = 0; ks < 4; ++ks) {
        bf16x8 ba = *(const bf16x8*)(udW1aT + (nb*16 + lr)*128 + ks*32 + lg*8);
        accP = __builtin_amdgcn_mfma_f32_16x16x32_bf16(a[ks], ba, accP, 0, 0, 0);
        bf16x8 bb = *(const bf16x8*)(udW1bT + (nb*16 + lr)*128 + ks*32 + lg*8);
        accQ = __builtin_amdgcn_mfma_f32_16x16x32_bf16(a[ks], bb, accQ, 0, 0, 0);
      }
      int n = nb*16 + lr;
      #pragma unroll
      for (int r = 0; r < 4; ++r) {
        int row = w*16 + lg*4 + r;
        Pout[row*128 + n] = accP[r];
        Qout[row*128 + n] = accQ[r];
      }
    }
  }
}

// ---------------------------------------------------------------------------
// K2: edge encoder -> 32-dim codes E2 (bf16). One thread per edge.
// ---------------------------------------------------------------------------
__global__ __launch_bounds__(256) void k2_edge(
    const float* __restrict__ edge_w,
    const float* __restrict__ eeW1, const float* __restrict__ eeb1,
    const float* __restrict__ eeW2, const float* __restrict__ eeb2,
    bf16_t* __restrict__ E2g) {
  __shared__ float sW2[1024];
  for (int f = threadIdx.x; f < 1024; f += 256) sW2[f] = eeW2[f];
  __syncthreads();
  int e = blockIdx.x * 256 + threadIdx.x;         // 0..18431
  int g = e / 9216, r = e % 9216, i = r / 96, j = r % 96;
  float wv = edge_w[(g*96 + i)*192 + (g*96 + j)];
  float h[32];
  #pragma unroll
  for (int m = 0; m < 32; ++m) h[m] = fmaxf(wv * eeW1[m] + eeb1[m], 0.f);
  #pragma unroll
  for (int n = 0; n < 32; ++n) {
    float acc = eeb2[n];
    #pragma unroll
    for (int m = 0; m < 32; ++m) acc += h[m] * sW2[m*32 + n];
    E2g[(size_t)e*32 + n] = (bf16_t)fmaxf(acc, 0.f);
  }
}

// ---------------------------------------------------------------------------
// K3: main edge MLP. Block = (g, i-tile(8), j-tile(8), t-chunk(8)), 4 waves.
//   Cs  = E2_tile @ W1c          (MFMA, once per block, reused over 8 t)
//   h1  = relu(P[t+1,i]+Q[t,j]+Cs+b1)  (VALU -> LDS bf16)
//   h2  = relu(h1@W2+b2); logit = h2@W3+b3  (MFMA + in-reg reduce)
// ---------------------------------------------------------------------------
__global__ __launch_bounds__(256) void k3_main(
    const float* __restrict__ P, const float* __restrict__ Q,
    const bf16_t* __restrict__ E2g, const bf16_t* __restrict__ W1cT,
    const bf16_t* __restrict__ udW2T,
    const float* __restrict__ udb1, const float* __restrict__ udb2,
    const float* __restrict__ udW3, const float* __restrict__ udb3,
    const float* __restrict__ edge_w,
    float* __restrict__ out_logits) {
  __shared__ bf16_t Cs[64 * XS_LD];
  __shared__ bf16_t H1s[64 * XS_LD];
  int jt = blockIdx.x, it = blockIdx.y, z = blockIdx.z;
  int g = z >> 2, tc = z & 3;
  int i0 = it * 8, j0 = jt * 8;
  int tid = threadIdx.x;
  int l = tid & 63, w = tid >> 6, lr = l & 15, lg = l >> 4;

  // preload layer-2 B-fragments (udW2T: [64][128]) and per-lane b2/W3
  bf16x8 wb[4][4];
  #pragma unroll
  for (int nb = 0; nb < 4; ++nb)
    #pragma unroll
    for (int ks = 0; ks < 4; ++ks)
      wb[nb][ks] = *(const bf16x8*)(udW2T + (nb*16 + lr)*128 + ks*32 + lg*8);
  float b2v[4], w3v[4];
  #pragma unroll
  for (int nb = 0; nb < 4; ++nb) { b2v[nb] = udb2[nb*16 + lr]; w3v[nb] = udW3[nb*16 + lr]; }
  float b3 = udb3[0];

  // C tile: this wave's 16 edge-rows, K=32 single MFMA step
  {
    int e_loc = w*16 + lr;
    int ii = e_loc >> 3, jj = e_loc & 7;
    bf16x8 ae = *(const bf16x8*)(E2g + (size_t)((g*96 + i0 + ii)*96 + (j0 + jj))*32 + lg*8);
    #pragma unroll
    for (int nb = 0; nb < 8; ++nb) {
      bf16x8 bw = *(const bf16x8*)(W1cT + (nb*16 + lr)*32 + lg*8);
      f32x4 acc = {0.f,0.f,0.f,0.f};
      acc = __builtin_amdgcn_mfma_f32_16x16x32_bf16(ae, bw, acc, 0, 0, 0);
      #pragma unroll
      for (int r = 0; r < 4; ++r)
        Cs[(w*16 + lg*4 + r)*XS_LD + nb*16 + lr] = (bf16_t)acc[r];
    }
  }
  __syncthreads();

  for (int tt = 0; tt < 8; ++tt) {
    int t = tc*8 + tt;
    const float* Pb = P + (size_t)((g*33 + t + 1)*96 + i0) * 128;
    const float* Qb = Q + (size_t)((g*33 + t)*96 + j0) * 128;
    // phase A: build h1 (bf16) in LDS
    for (int f = tid; f < 64*64; f += 256) {
      int e = f >> 6, k = (f & 63) * 2;
      int ii = e >> 3, jj = e & 7;
      f32x2 p  = *(const f32x2*)(Pb + ii*128 + k);
      f32x2 q  = *(const f32x2*)(Qb + jj*128 + k);
      f32x2 b1 = *(const f32x2*)(udb1 + k);
      float c0 = (float)Cs[e*XS_LD + k];
      float c1 = (float)Cs[e*XS_LD + k + 1];
      bf16x2 hv;
      hv[0] = (bf16_t)fmaxf(p[0] + q[0] + c0 + b1[0], 0.f);
      hv[1] = (bf16_t)fmaxf(p[1] + q[1] + c1 + b1[1], 0.f);
      *(bf16x2*)(H1s + e*XS_LD + k) = hv;
    }
    __syncthreads();
    // phase B: h2 via MFMA, logit via in-register reduce
    bf16x8 a[4];
    #pragma unroll
    for (int ks = 0; ks < 4; ++ks)
      a[ks] = *(const bf16x8*)(H1s + (w*16 + lr)*XS_LD + ks*32 + lg*8);
    f32x4 acc[4];
    #pragma unroll
    for (int nb = 0; nb < 4; ++nb) {
      f32x4 t4 = {0.f,0.f,0.f,0.f};
      #pragma unroll
      for (int ks = 0; ks < 4; ++ks)
        t4 = __builtin_amdgcn_mfma_f32_16x16x32_bf16(a[ks], wb[nb][ks], t4, 0, 0, 0);
      acc[nb] = t4;
    }
    float partial[4];
    #pragma unroll
    for (int r = 0; r < 4; ++r) {
      float ps = 0.f;
      #pragma unroll
      for (int nb = 0; nb < 4; ++nb)
        ps += fmaxf(acc[nb][r] + b2v[nb], 0.f) * w3v[nb];
      partial[r] = ps;
    }
    #pragma unroll
    for (int r = 0; r < 4; ++r) {
      partial[r] += __shfl_xor(partial[r], 1, 16);
      partial[r] += __shfl_xor(partial[r], 2, 16);
      partial[r] += __shfl_xor(partial[r], 4, 16);
      partial[r] += __shfl_xor(partial[r], 8, 16);
    }
    if (lr < 4) {
      float v = (lr == 0) ? partial[0] : (lr == 1) ? partial[1]
              : (lr == 2) ? partial[2] : partial[3];
      v += b3;
      int row = w*16 + lg*4 + lr;
      int i = i0 + (row >> 3), j = j0 + (row & 7);
      float ew = edge_w[(g*96 + i)*192 + (g*96 + j)];
      if (ew == 0.0f && i != j) v = NEGV;
      out_logits[(size_t)((g*32 + t)*96 + i) * 96 + j] = v;
    }
    __syncthreads();
  }
}

// ---------------------------------------------------------------------------
// K4: dist head. Block per (g,t), 6 waves, M=96.
//   input = concat(enc[t], enc[t+1]) (K=256), 128 relu, 64 relu, 1.
// ---------------------------------------------------------------------------
__global__ __launch_bounds__(384) void k4_dist(
    const bf16_t* __restrict__ encB,
    const bf16_t* __restrict__ dpW1T, const float* __restrict__ dpb1,
    const bf16_t* __restrict__ dpW2T, const float* __restrict__ dpb2,
    const float* __restrict__ dpW3, const float* __restrict__ dpb3,
    float* __restrict__ dist_out) {
  __shared__ bf16_t h1buf[96 * XS_LD];
  int t = blockIdx.x, g = blockIdx.y;
  int l = threadIdx.x & 63, w = threadIdx.x >> 6, lr = l & 15, lg = l >> 4;

  // layer1: A from global encB (first 128 = enc[t] (xce), last 128 = enc[t+1] (xne))
  {
    bf16x8 a[8];
    #pragma unroll
    for (int ks = 0; ks < 8; ++ks) {
      int half = ks >> 2;
      int kk = (ks & 3)*32 + lg*8;
      a[ks] = *(const bf16x8*)(encB + (size_t)((g*33 + t + half)*96 + (w*16 + lr))*128 + kk);
    }
    #pragma unroll
    for (int nb = 0; nb < 8; ++nb) {
      f32x4 acc = {0.f,0.f,0.f,0.f};
      #pragma unroll
      for (int ks = 0; ks < 8; ++ks) {
        bf16x8 bfr = *(const bf16x8*)(dpW1T + (size_t)(nb*16 + lr)*256 + ks*32 + lg*8);
        acc = __builtin_amdgcn_mfma_f32_16x16x32_bf16(a[ks], bfr, acc, 0, 0, 0);
      }
      int n = nb*16 + lr; float bv = dpb1[n];
      #pragma unroll
      for (int r = 0; r < 4; ++r)
        h1buf[(w*16 + lg*4 + r)*XS_LD + n] = (bf16_t)fmaxf(acc[r] + bv, 0.f);
    }
  }
  __syncthreads();

  // layer2 + epilogue
  bf16x8 a2[4];
  #pragma unroll
  for (int ks = 0; ks < 4; ++ks)
    a2[ks] = *(const bf16x8*)(h1buf + (w*16 + lr)*XS_LD + ks*32 + lg*8);
  f32x4 acc[4];
  #pragma unroll
  for (int nb = 0; nb < 4; ++nb) {
    f32x4 t4 = {0.f,0.f,0.f,0.f};
    #pragma unroll
    for (int ks = 0; ks < 4; ++ks) {
      bf16x8 bfr = *(const bf16x8*)(dpW2T + (nb*16 + lr)*128 + ks*32 + lg*8);
      t4 = __builtin_amdgcn_mfma_f32_16x16x32_bf16(a2[ks], bfr, t4, 0, 0, 0);
    }
    acc[nb] = t4;
  }
  float b2v[4], w3v[4];
  #pragma unroll
  for (int nb = 0; nb < 4; ++nb) { b2v[nb] = dpb2[nb*16 + lr]; w3v[nb] = dpW3[nb*16 + lr]; }
  float partial[4];
  #pragma unroll
  for (int r = 0; r < 4; ++r) {
    float ps = 0.f;
    #pragma unroll
    for (int nb = 0; nb < 4; ++nb)
      ps += fmaxf(acc[nb][r] + b2v[nb], 0.f) * w3v[nb];
    partial[r] = ps;
  }
  #pragma unroll
  for (int r = 0; r < 4; ++r) {
    partial[r] += __shfl_xor(partial[r], 1, 16);
    partial[r] += __shfl_xor(partial[r], 2, 16);
    partial[r] += __shfl_xor(partial[r], 4, 16);
    partial[r] += __shfl_xor(partial[r], 8, 16);
  }
  if (lr < 4) {
    float v = (lr == 0) ? partial[0] : (lr == 1) ? partial[1]
            : (lr == 2) ? partial[2] : partial[3];
    v += dpb3[0];
    int row = w*16 + lg*4 + lr;
    dist_out[(size_t)(g*32 + t)*96 + row] = v;
  }
}

// ---------------------------------------------------------------------------
extern "C" void kernel_launch(void* const* d_in, const int* in_sizes, int n_in,
                              void* d_out, int out_size, void* d_ws, size_t ws_size,
                              hipStream_t stream) {
  (void)in_sizes; (void)n_in; (void)out_size; (void)ws_size;
  const float* x      = (const float*)d_in[0];
  const float* edge_w = (const float*)d_in[1];
  const float* neW1 = (const float*)d_in[5];
  const float* neb1 = (const float*)d_in[6];
  const float* neW2 = (const float*)d_in[7];
  const float* neb2 = (const float*)d_in[8];
  const float* eeW1 = (const float*)d_in[9];
  const float* eeb1 = (const float*)d_in[10];
  const float* eeW2 = (const float*)d_in[11];
  const float* eeb2 = (const float*)d_in[12];
  const float* udW1 = (const float*)d_in[13];
  const float* udb1 = (const float*)d_in[14];
  const float* udW2 = (const float*)d_in[15];
  const float* udb2 = (const float*)d_in[16];
  const float* udW3 = (const float*)d_in[17];
  const float* udb3 = (const float*)d_in[18];
  const float* dpW1 = (const float*)d_in[19];
  const float* dpb1 = (const float*)d_in[20];
  const float* dpW2 = (const float*)d_in[21];
  const float* dpb2 = (const float*)d_in[22];
  const float* dpW3 = (const float*)d_in[23];
  const float* dpb3 = (const float*)d_in[24];

  char* ws = (char*)d_ws;
  size_t off = 0;
  auto alloc = [&](size_t bytes) -> char* {
    off = (off + 255) & ~(size_t)255;
    char* p = ws + off;
    off += bytes;
    return p;
  };
  bf16_t* encB   = (bf16_t*)alloc((size_t)2*33*96*128 * 2);
  float*  Pbuf   = (float*) alloc((size_t)2*33*96*128 * 4);
  float*  Qbuf   = (float*) alloc((size_t)2*33*96*128 * 4);
  bf16_t* E2g    = (bf16_t*)alloc((size_t)2*96*96*32  * 2);
  bf16_t* neW1T  = (bf16_t*)alloc(16384 * 2);
  bf16_t* neW2T  = (bf16_t*)alloc(16384 * 2);
  bf16_t* udW1aT = (bf16_t*)alloc(16384 * 2);
  bf16_t* udW1bT = (bf16_t*)alloc(16384 * 2);
  bf16_t* udW2T  = (bf16_t*)alloc(8192  * 2);
  bf16_t* dpW1T  = (bf16_t*)alloc(32768 * 2);
  bf16_t* dpW2T  = (bf16_t*)alloc(8192  * 2);
  bf16_t* W1cT   = (bf16_t*)alloc(4096  * 2);

  float* out_logits = (float*)d_out;                 // (2,32,96,96)
  float* dist_out   = (float*)d_out + 2*32*96*96;    // (2,32,96)

  k0_prep<<<dim3(464), dim3(256), 0, stream>>>(
      neW1, neW2, udW1, udW2, dpW1, dpW2,
      neW1T, neW2T, udW1aT, udW1bT, udW2T, dpW1T, dpW2T, W1cT);

  k1_node<<<dim3(66), dim3(384), 0, stream>>>(
      x, neW1T, neb1, neW2T, neb2, udW1aT, udW1bT, encB, Pbuf, Qbuf);

  k2_edge<<<dim3(72), dim3(256), 0, stream>>>(
      edge_w, eeW1, eeb1, eeW2, eeb2, E2g);

  k3_main<<<dim3(12, 12, 8), dim3(256), 0, stream>>>(
      Pbuf, Qbuf, E2g, W1cT, udW2T, udb1, udb2, udW3, udb3, edge_w, out_logits);

  k4_dist<<<dim3(32, 2), dim3(384), 0, stream>>>(
      encB, dpW1T, dpb1, dpW2T, dpb2, dpW3, dpb3, dist_out);
}

// Round 3
// 187.870 us; speedup vs baseline: 1.4050x; 1.4050x over previous
//
#include <hip/hip_runtime.h>

// ---------------------------------------------------------------------------
// InterpNetwork: G=2, T=33, D=96, H=128, PROJ=128.
// feat@ud_W1 = P[t+1,i] + Q[t,j] + C[i,j]  (concat split) =>
// per-edge work = layer2 (128->64) + layer3 (64->1) via MFMA.
// k3 v2: P/Q slabs staged to LDS once per block; b1 folded into Cs;
//        zero barriers / zero global loads in the t-loop.
// ---------------------------------------------------------------------------

typedef __bf16 bf16_t;
typedef bf16_t bf16x8 __attribute__((ext_vector_type(8)));
typedef float  f32x4  __attribute__((ext_vector_type(4)));

#define XS_LD 136
#define NEGV  -1000000000.0f

// ---------------------------------------------------------------------------
// K0: tiled transposes f32[K][N] -> bf16[N][K] (coalesced both sides).
// ---------------------------------------------------------------------------
__global__ __launch_bounds__(256) void k0_prep(
    const float* __restrict__ neW1, const float* __restrict__ neW2,
    const float* __restrict__ udW1, const float* __restrict__ udW2,
    const float* __restrict__ dpW1, const float* __restrict__ dpW2,
    const float* __restrict__ eeW2,
    bf16_t* __restrict__ neW1T, bf16_t* __restrict__ neW2T,
    bf16_t* __restrict__ udW1aT, bf16_t* __restrict__ udW1bT,
    bf16_t* __restrict__ W1cT, bf16_t* __restrict__ udW2T,
    bf16_t* __restrict__ dpW1T, bf16_t* __restrict__ dpW2T,
    bf16_t* __restrict__ W2eT) {
  static const unsigned char tSrc[31] = {0,0,0,0, 1,1,1,1, 2,2,2,2, 2,2,2,2, 2,2, 3,3, 4,4,4,4,4,4,4,4, 5,5, 6};
  static const unsigned char tDst[31] = {0,0,0,0, 1,1,1,1, 2,2,2,2, 3,3,3,3, 4,4, 5,5, 6,6,6,6,6,6,6,6, 7,7, 8};
  static const short tLdS[31] = {128,128,128,128, 128,128,128,128, 128,128,128,128, 128,128,128,128, 128,128, 64,64, 128,128,128,128,128,128,128,128, 64,64, 32};
  static const short tLdD[31] = {128,128,128,128, 128,128,128,128, 128,128,128,128, 128,128,128,128, 32,32, 128,128, 256,256,256,256,256,256,256,256, 128,128, 32};
  static const short tR0[31]  = {0,0,64,64, 0,0,64,64, 0,0,64,64, 128,128,192,192, 256,256, 0,64, 0,0,64,64,128,128,192,192, 0,64, 0};
  static const short tC0[31]  = {0,64,0,64, 0,64,0,64, 0,64,0,64, 0,64,0,64, 0,64, 0,0, 0,64,0,64,0,64,0,64, 0,0, 0};
  static const short tRB[31]  = {0,0,0,0, 0,0,0,0, 0,0,0,0, 128,128,128,128, 256,256, 0,0, 0,0,0,0,0,0,0,0, 0,0, 0};
  static const unsigned char tNR[31] = {64,64,64,64, 64,64,64,64, 64,64,64,64, 64,64,64,64, 32,32, 64,64, 64,64,64,64,64,64,64,64, 64,64, 32};
  static const unsigned char tNC[31] = {64,64,64,64, 64,64,64,64, 64,64,64,64, 64,64,64,64, 64,64, 64,64, 64,64,64,64,64,64,64,64, 64,64, 32};

  int b = blockIdx.x;
  const float* S;
  switch (tSrc[b]) {
    case 0: S = neW1; break; case 1: S = neW2; break; case 2: S = udW1; break;
    case 3: S = udW2; break; case 4: S = dpW1; break; case 5: S = dpW2; break;
    default: S = eeW2; break;
  }
  bf16_t* Dst;
  switch (tDst[b]) {
    case 0: Dst = neW1T; break; case 1: Dst = neW2T; break; case 2: Dst = udW1aT; break;
    case 3: Dst = udW1bT; break; case 4: Dst = W1cT; break; case 5: Dst = udW2T; break;
    case 6: Dst = dpW1T; break; case 7: Dst = dpW2T; break; default: Dst = W2eT; break;
  }
  int ldS = tLdS[b], ldD = tLdD[b], r0 = tR0[b], c0 = tC0[b], rb = tRB[b];
  int nR = tNR[b], nC = tNC[b];

  __shared__ float tile[64][65];
  #pragma unroll
  for (int i = 0; i < 16; ++i) {
    int idx = threadIdx.x + i * 256, r = idx >> 6, c = idx & 63;
    if (r < nR && c < nC) tile[r][c] = S[(r0 + r) * ldS + c0 + c];
  }
  __syncthreads();
  #pragma unroll
  for (int i = 0; i < 16; ++i) {
    int idx = threadIdx.x + i * 256, n = idx >> 6, k = idx & 63;
    if (n < nC && k < nR) Dst[(c0 + n) * ldD + (r0 - rb) + k] = (bf16_t)tile[k][n];
  }
}

// ---------------------------------------------------------------------------
// K1: node encoder (L1+L2 only). One block per (g,s), 6 waves, M=96.
// ---------------------------------------------------------------------------
__global__ __launch_bounds__(384) void k1_node(
    const float* __restrict__ x,
    const bf16_t* __restrict__ neW1T, const float* __restrict__ neb1,
    const bf16_t* __restrict__ neW2T, const float* __restrict__ neb2,
    bf16_t* __restrict__ encB) {
  __shared__ bf16_t bufA[96 * XS_LD];
  __shared__ bf16_t bufB[96 * XS_LD];
  int b = blockIdx.x; int g = b / 33;
  const float* xsrc = x + (size_t)b * 128 * 192 + g * 96;   // [h*192 + d]
  #pragma unroll
  for (int i = 0; i < 8; ++i) {
    int cidx = threadIdx.x + i * 384;            // 0..3071 (chunks of 4 d's)
    int h = cidx / 24, dc = (cidx % 24) * 4;
    f32x4 v = *(const f32x4*)(xsrc + h * 192 + dc);
    #pragma unroll
    for (int r = 0; r < 4; ++r) bufA[(dc + r) * XS_LD + h] = (bf16_t)v[r];
  }
  __syncthreads();
  int l = threadIdx.x & 63, w = threadIdx.x >> 6, lr = l & 15, lg = l >> 4;

  // layer1: bufA -> bufB
  {
    bf16x8 a[4];
    #pragma unroll
    for (int ks = 0; ks < 4; ++ks)
      a[ks] = *(const bf16x8*)(bufA + (w*16 + lr)*XS_LD + ks*32 + lg*8);
    #pragma unroll
    for (int nb = 0; nb < 8; ++nb) {
      f32x4 acc = {0.f,0.f,0.f,0.f};
      #pragma unroll
      for (int ks = 0; ks < 4; ++ks) {
        bf16x8 bfr = *(const bf16x8*)(neW1T + (nb*16 + lr)*128 + ks*32 + lg*8);
        acc = __builtin_amdgcn_mfma_f32_16x16x32_bf16(a[ks], bfr, acc, 0, 0, 0);
      }
      int n = nb*16 + lr; float bv = neb1[n];
      #pragma unroll
      for (int r = 0; r < 4; ++r)
        bufB[(w*16 + lg*4 + r)*XS_LD + n] = (bf16_t)fmaxf(acc[r] + bv, 0.f);
    }
  }
  __syncthreads();

  // layer2: bufB -> encB(global)
  bf16_t* encOut = encB + (size_t)b * 96 * 128;
  {
    bf16x8 a[4];
    #pragma unroll
    for (int ks = 0; ks < 4; ++ks)
      a[ks] = *(const bf16x8*)(bufB + (w*16 + lr)*XS_LD + ks*32 + lg*8);
    #pragma unroll
    for (int nb = 0; nb < 8; ++nb) {
      f32x4 acc = {0.f,0.f,0.f,0.f};
      #pragma unroll
      for (int ks = 0; ks < 4; ++ks) {
        bf16x8 bfr = *(const bf16x8*)(neW2T + (nb*16 + lr)*128 + ks*32 + lg*8);
        acc = __builtin_amdgcn_mfma_f32_16x16x32_bf16(a[ks], bfr, acc, 0, 0, 0);
      }
      int n = nb*16 + lr; float bv = neb2[n];
      #pragma unroll
      for (int r = 0; r < 4; ++r)
        encOut[(w*16 + lg*4 + r)*128 + n] = (bf16_t)fmaxf(acc[r] + bv, 0.f);
    }
  }
}

// ---------------------------------------------------------------------------
// KM: merged P/Q projection (blocks 0..263) + edge encoder via MFMA (264..455).
//   PQ: block = (gs, quad); quad 0/1 -> P cols 0-63/64-127, 2/3 -> Q.
//   E2: 96 edges per block, h1e in-reg -> 2 MFMAs vs W2eT.
// ---------------------------------------------------------------------------
__global__ __launch_bounds__(384) void km_pq_e2(
    const bf16_t* __restrict__ encB,
    const bf16_t* __restrict__ udW1aT, const bf16_t* __restrict__ udW1bT,
    bf16_t* __restrict__ P, bf16_t* __restrict__ Q,
    const float* __restrict__ edge_w,
    const float* __restrict__ eeW1, const float* __restrict__ eeb1,
    const bf16_t* __restrict__ W2eT, const float* __restrict__ eeb2,
    bf16_t* __restrict__ E2g) {
  int b = blockIdx.x;
  int l = threadIdx.x & 63, w = threadIdx.x >> 6, lr = l & 15, lg = l >> 4;
  if (b < 264) {
    int gs = b >> 2, quad = b & 3;
    const bf16_t* BW = (quad < 2) ? udW1aT : udW1bT;
    bf16_t* out = (quad < 2) ? P : Q;
    int noff = (quad & 1) * 64;
    bf16x8 a[4];
    #pragma unroll
    for (int ks = 0; ks < 4; ++ks)
      a[ks] = *(const bf16x8*)(encB + ((size_t)gs*96 + w*16 + lr)*128 + ks*32 + lg*8);
    #pragma unroll
    for (int nb = 0; nb < 4; ++nb) {
      f32x4 acc = {0.f,0.f,0.f,0.f};
      #pragma unroll
      for (int ks = 0; ks < 4; ++ks) {
        bf16x8 bfr = *(const bf16x8*)(BW + (noff + nb*16 + lr)*128 + ks*32 + lg*8);
        acc = __builtin_amdgcn_mfma_f32_16x16x32_bf16(a[ks], bfr, acc, 0, 0, 0);
      }
      #pragma unroll
      for (int r = 0; r < 4; ++r)
        out[((size_t)gs*96 + w*16 + lg*4 + r)*128 + noff + nb*16 + lr] = (bf16_t)acc[r];
    }
  } else {
    int eb = b - 264;
    int e0 = eb * 96 + w * 16;            // this wave's first edge
    int e = e0 + lr;
    int g = e / 9216, rem = e - g * 9216, i = rem / 96, j = rem - i * 96;
    float wv = edge_w[(g*96 + i)*192 + g*96 + j];
    bf16x8 ah;
    #pragma unroll
    for (int m = 0; m < 8; ++m) {
      int k = lg*8 + m;
      ah[m] = (bf16_t)fmaxf(wv * eeW1[k] + eeb1[k], 0.f);
    }
    #pragma unroll
    for (int nb = 0; nb < 2; ++nb) {
      bf16x8 bw = *(const bf16x8*)(W2eT + (nb*16 + lr)*32 + lg*8);
      f32x4 acc = {0.f,0.f,0.f,0.f};
      acc = __builtin_amdgcn_mfma_f32_16x16x32_bf16(ah, bw, acc, 0, 0, 0);
      float b2 = eeb2[nb*16 + lr];
      #pragma unroll
      for (int r = 0; r < 4; ++r)
        E2g[((size_t)e0 + lg*4 + r)*32 + nb*16 + lr] = (bf16_t)fmaxf(acc[r] + b2, 0.f);
    }
  }
}

// ---------------------------------------------------------------------------
// K3 v2: block = (jt, it, g*4+tc), 4 waves. P/Q slabs staged to LDS once;
// Cs = E2@W1c + b1; t-loop has zero barriers and zero global loads.
// ---------------------------------------------------------------------------
__global__ __launch_bounds__(256) void k3_main(
    const bf16_t* __restrict__ P, const bf16_t* __restrict__ Q,
    const bf16_t* __restrict__ E2g, const bf16_t* __restrict__ W1cT,
    const bf16_t* __restrict__ udW2T,
    const float* __restrict__ udb1, const float* __restrict__ udb2,
    const float* __restrict__ udW3, const float* __restrict__ udb3,
    const float* __restrict__ edge_w,
    float* __restrict__ out_logits) {
  __shared__ bf16_t Cs[64 * XS_LD];
  __shared__ bf16_t Ps[64 * XS_LD];
  __shared__ bf16_t Qs[64 * XS_LD];
  int jt = blockIdx.x, it = blockIdx.y, z = blockIdx.z;
  int g = z >> 2, tc = z & 3;
  int i0 = it * 8, j0 = jt * 8;
  int tid = threadIdx.x;
  int l = tid & 63, w = tid >> 6, lr = l & 15, lg = l >> 4;
  int e_loc = w * 16 + lr, ii = e_loc >> 3, jj = e_loc & 7;

  // ---- issue P/Q slab loads (bf16, 8x16B per thread) ----
  bf16x8 pst[4], qst[4];
  #pragma unroll
  for (int r = 0; r < 4; ++r) {
    int c = tid + r * 256;                 // 0..1023
    int row = c >> 4, kc = c & 15;         // row = tt*8+rr
    int tt = row >> 3, rr = row & 7;
    pst[r] = *(const bf16x8*)(P + ((size_t)((g*33 + tc*8 + tt + 1)*96) + i0 + rr)*128 + kc*8);
    qst[r] = *(const bf16x8*)(Q + ((size_t)((g*33 + tc*8 + tt)*96) + j0 + rr)*128 + kc*8);
  }

  // ---- preload weights / biases ----
  bf16x8 wb[4][4];
  #pragma unroll
  for (int nb = 0; nb < 4; ++nb)
    #pragma unroll
    for (int ks = 0; ks < 4; ++ks)
      wb[nb][ks] = *(const bf16x8*)(udW2T + (nb*16 + lr)*128 + ks*32 + lg*8);
  float b2v[4], w3v[4], b1v[8];
  #pragma unroll
  for (int nb = 0; nb < 4; ++nb) { b2v[nb] = udb2[nb*16 + lr]; w3v[nb] = udW3[nb*16 + lr]; }
  #pragma unroll
  for (int nb = 0; nb < 8; ++nb) b1v[nb] = udb1[nb*16 + lr];
  float b3 = udb3[0];

  // ---- mask (hoisted; valid for lanes lr<4 at store) ----
  int orow = w*16 + lg*4 + (lr & 3);
  int mi = i0 + (orow >> 3), mj = j0 + (orow & 7);
  float ewv = edge_w[(g*96 + mi)*192 + g*96 + mj];
  bool dead = (ewv == 0.0f) && (mi != mj);

  // ---- C tile: Cs = E2 @ W1c + b1 ----
  {
    bf16x8 ae = *(const bf16x8*)(E2g + ((size_t)((g*96 + i0 + ii)*96) + j0 + jj)*32 + lg*8);
    #pragma unroll
    for (int nb = 0; nb < 8; ++nb) {
      bf16x8 bw = *(const bf16x8*)(W1cT + (nb*16 + lr)*32 + lg*8);
      f32x4 acc = {0.f,0.f,0.f,0.f};
      acc = __builtin_amdgcn_mfma_f32_16x16x32_bf16(ae, bw, acc, 0, 0, 0);
      #pragma unroll
      for (int r = 0; r < 4; ++r)
        Cs[(w*16 + lg*4 + r)*XS_LD + nb*16 + lr] = (bf16_t)(acc[r] + b1v[nb]);
    }
  }

  // ---- write slabs to LDS, one barrier ----
  #pragma unroll
  for (int r = 0; r < 4; ++r) {
    int c = tid + r * 256;
    int row = c >> 4, kc = c & 15;
    *(bf16x8*)(Ps + row*XS_LD + kc*8) = pst[r];
    *(bf16x8*)(Qs + row*XS_LD + kc*8) = qst[r];
  }
  __syncthreads();

  // ---- hoist this lane's Cs fragment to f32 ----
  float csf[32];
  #pragma unroll
  for (int ks = 0; ks < 4; ++ks) {
    bf16x8 cv = *(const bf16x8*)(Cs + e_loc*XS_LD + ks*32 + lg*8);
    #pragma unroll
    for (int m = 0; m < 8; ++m) csf[ks*8 + m] = (float)cv[m];
  }

  // ---- t-loop: no barriers, no global loads ----
  #pragma unroll 2
  for (int tt = 0; tt < 8; ++tt) {
    int prow = tt*8 + ii, qrow = tt*8 + jj;
    bf16x8 a[4];
    #pragma unroll
    for (int ks = 0; ks < 4; ++ks) {
      bf16x8 pv = *(const bf16x8*)(Ps + prow*XS_LD + ks*32 + lg*8);
      bf16x8 qv = *(const bf16x8*)(Qs + qrow*XS_LD + ks*32 + lg*8);
      #pragma unroll
      for (int m = 0; m < 8; ++m) {
        float s = (float)pv[m] + (float)qv[m] + csf[ks*8 + m];
        a[ks][m] = (bf16_t)fmaxf(s, 0.f);
      }
    }
    f32x4 acc[4];
    #pragma unroll
    for (int nb = 0; nb < 4; ++nb) {
      f32x4 t4 = {0.f,0.f,0.f,0.f};
      #pragma unroll
      for (int ks = 0; ks < 4; ++ks)
        t4 = __builtin_amdgcn_mfma_f32_16x16x32_bf16(a[ks], wb[nb][ks], t4, 0, 0, 0);
      acc[nb] = t4;
    }
    float partial[4];
    #pragma unroll
    for (int r = 0; r < 4; ++r) {
      float ps = 0.f;
      #pragma unroll
      for (int nb = 0; nb < 4; ++nb)
        ps += fmaxf(acc[nb][r] + b2v[nb], 0.f) * w3v[nb];
      partial[r] = ps;
    }
    #pragma unroll
    for (int r = 0; r < 4; ++r) {
      partial[r] += __shfl_xor(partial[r], 1, 16);
      partial[r] += __shfl_xor(partial[r], 2, 16);
      partial[r] += __shfl_xor(partial[r], 4, 16);
      partial[r] += __shfl_xor(partial[r], 8, 16);
    }
    if (lr < 4) {
      float v = (lr == 0) ? partial[0] : (lr == 1) ? partial[1]
              : (lr == 2) ? partial[2] : partial[3];
      v = dead ? NEGV : (v + b3);
      out_logits[(size_t)((g*32 + tc*8 + tt)*96 + mi)*96 + mj] = v;
    }
  }
}

// ---------------------------------------------------------------------------
// K4: dist head. Block per (g,t), 6 waves, M=96. K=256 -> 128 -> 64 -> 1.
// ---------------------------------------------------------------------------
__global__ __launch_bounds__(384) void k4_dist(
    const bf16_t* __restrict__ encB,
    const bf16_t* __restrict__ dpW1T, const float* __restrict__ dpb1,
    const bf16_t* __restrict__ dpW2T, const float* __restrict__ dpb2,
    const float* __restrict__ dpW3, const float* __restrict__ dpb3,
    float* __restrict__ dist_out) {
  __shared__ bf16_t h1buf[96 * XS_LD];
  int t = blockIdx.x, g = blockIdx.y;
  int l = threadIdx.x & 63, w = threadIdx.x >> 6, lr = l & 15, lg = l >> 4;

  {
    bf16x8 a[8];
    #pragma unroll
    for (int ks = 0; ks < 8; ++ks) {
      int half = ks >> 2;
      int kk = (ks & 3)*32 + lg*8;
      a[ks] = *(const bf16x8*)(encB + (size_t)((g*33 + t + half)*96 + (w*16 + lr))*128 + kk);
    }
    #pragma unroll
    for (int nb = 0; nb < 8; ++nb) {
      f32x4 acc = {0.f,0.f,0.f,0.f};
      #pragma unroll
      for (int ks = 0; ks < 8; ++ks) {
        bf16x8 bfr = *(const bf16x8*)(dpW1T + (size_t)(nb*16 + lr)*256 + ks*32 + lg*8);
        acc = __builtin_amdgcn_mfma_f32_16x16x32_bf16(a[ks], bfr, acc, 0, 0, 0);
      }
      int n = nb*16 + lr; float bv = dpb1[n];
      #pragma unroll
      for (int r = 0; r < 4; ++r)
        h1buf[(w*16 + lg*4 + r)*XS_LD + n] = (bf16_t)fmaxf(acc[r] + bv, 0.f);
    }
  }
  __syncthreads();

  bf16x8 a2[4];
  #pragma unroll
  for (int ks = 0; ks < 4; ++ks)
    a2[ks] = *(const bf16x8*)(h1buf + (w*16 + lr)*XS_LD + ks*32 + lg*8);
  f32x4 acc[4];
  #pragma unroll
  for (int nb = 0; nb < 4; ++nb) {
    f32x4 t4 = {0.f,0.f,0.f,0.f};
    #pragma unroll
    for (int ks = 0; ks < 4; ++ks) {
      bf16x8 bfr = *(const bf16x8*)(dpW2T + (nb*16 + lr)*128 + ks*32 + lg*8);
      t4 = __builtin_amdgcn_mfma_f32_16x16x32_bf16(a2[ks], bfr, t4, 0, 0, 0);
    }
    acc[nb] = t4;
  }
  float b2v[4], w3v[4];
  #pragma unroll
  for (int nb = 0; nb < 4; ++nb) { b2v[nb] = dpb2[nb*16 + lr]; w3v[nb] = dpW3[nb*16 + lr]; }
  float partial[4];
  #pragma unroll
  for (int r = 0; r < 4; ++r) {
    float ps = 0.f;
    #pragma unroll
    for (int nb = 0; nb < 4; ++nb)
      ps += fmaxf(acc[nb][r] + b2v[nb], 0.f) * w3v[nb];
    partial[r] = ps;
  }
  #pragma unroll
  for (int r = 0; r < 4; ++r) {
    partial[r] += __shfl_xor(partial[r], 1, 16);
    partial[r] += __shfl_xor(partial[r], 2, 16);
    partial[r] += __shfl_xor(partial[r], 4, 16);
    partial[r] += __shfl_xor(partial[r], 8, 16);
  }
  if (lr < 4) {
    float v = (lr == 0) ? partial[0] : (lr == 1) ? partial[1]
            : (lr == 2) ? partial[2] : partial[3];
    v += dpb3[0];
    int row = w*16 + lg*4 + lr;
    dist_out[(size_t)(g*32 + t)*96 + row] = v;
  }
}

// ---------------------------------------------------------------------------
extern "C" void kernel_launch(void* const* d_in, const int* in_sizes, int n_in,
                              void* d_out, int out_size, void* d_ws, size_t ws_size,
                              hipStream_t stream) {
  (void)in_sizes; (void)n_in; (void)out_size; (void)ws_size;
  const float* x      = (const float*)d_in[0];
  const float* edge_w = (const float*)d_in[1];
  const float* neW1 = (const float*)d_in[5];
  const float* neb1 = (const float*)d_in[6];
  const float* neW2 = (const float*)d_in[7];
  const float* neb2 = (const float*)d_in[8];
  const float* eeW1 = (const float*)d_in[9];
  const float* eeb1 = (const float*)d_in[10];
  const float* eeW2 = (const float*)d_in[11];
  const float* eeb2 = (const float*)d_in[12];
  const float* udW1 = (const float*)d_in[13];
  const float* udb1 = (const float*)d_in[14];
  const float* udW2 = (const float*)d_in[15];
  const float* udb2 = (const float*)d_in[16];
  const float* udW3 = (const float*)d_in[17];
  const float* udb3 = (const float*)d_in[18];
  const float* dpW1 = (const float*)d_in[19];
  const float* dpb1 = (const float*)d_in[20];
  const float* dpW2 = (const float*)d_in[21];
  const float* dpb2 = (const float*)d_in[22];
  const float* dpW3 = (const float*)d_in[23];
  const float* dpb3 = (const float*)d_in[24];

  char* ws = (char*)d_ws;
  size_t off = 0;
  auto alloc = [&](size_t bytes) -> char* {
    off = (off + 255) & ~(size_t)255;
    char* p = ws + off;
    off += bytes;
    return p;
  };
  bf16_t* encB   = (bf16_t*)alloc((size_t)2*33*96*128 * 2);
  bf16_t* Pbuf   = (bf16_t*)alloc((size_t)2*33*96*128 * 2);
  bf16_t* Qbuf   = (bf16_t*)alloc((size_t)2*33*96*128 * 2);
  bf16_t* E2g    = (bf16_t*)alloc((size_t)2*96*96*32  * 2);
  bf16_t* neW1T  = (bf16_t*)alloc(16384 * 2);
  bf16_t* neW2T  = (bf16_t*)alloc(16384 * 2);
  bf16_t* udW1aT = (bf16_t*)alloc(16384 * 2);
  bf16_t* udW1bT = (bf16_t*)alloc(16384 * 2);
  bf16_t* W1cT   = (bf16_t*)alloc(4096  * 2);
  bf16_t* udW2T  = (bf16_t*)alloc(8192  * 2);
  bf16_t* dpW1T  = (bf16_t*)alloc(32768 * 2);
  bf16_t* dpW2T  = (bf16_t*)alloc(8192  * 2);
  bf16_t* W2eT   = (bf16_t*)alloc(1024  * 2);

  float* out_logits = (float*)d_out;                 // (2,32,96,96)
  float* dist_out   = (float*)d_out + 2*32*96*96;    // (2,32,96)

  k0_prep<<<dim3(31), dim3(256), 0, stream>>>(
      neW1, neW2, udW1, udW2, dpW1, dpW2, eeW2,
      neW1T, neW2T, udW1aT, udW1bT, W1cT, udW2T, dpW1T, dpW2T, W2eT);

  k1_node<<<dim3(66), dim3(384), 0, stream>>>(
      x, neW1T, neb1, neW2T, neb2, encB);

  km_pq_e2<<<dim3(456), dim3(384), 0, stream>>>(
      encB, udW1aT, udW1bT, Pbuf, Qbuf,
      edge_w, eeW1, eeb1, W2eT, eeb2, E2g);

  k3_main<<<dim3(12, 12, 8), dim3(256), 0, stream>>>(
      Pbuf, Qbuf, E2g, W1cT, udW2T, udb1, udb2, udW3, udb3, edge_w, out_logits);

  k4_dist<<<dim3(32, 2), dim3(384), 0, stream>>>(
      encB, dpW1T, dpb1, dpW2T, dpb2, dpW3, dpb3, dist_out);
}